// Round 1
// baseline (336.625 us; speedup 1.0000x reference)
//
#include <hip/hip_runtime.h>
#include <math.h>

#define NROWS 8192
#define NFEATD 500
#define NHID 128
#define NCLS 40
#define CAP 128   // max nnz/row capacity (actual ~16±4, max ~40)

// ---------------------------------------------------------------------------
// Kernel 1: degree + ordered CSR build. One wave per row.
// adj entries are exactly 0.0 or 1.0. deg = rowsum + 1 (identity).
// ---------------------------------------------------------------------------
__global__ void k_deg_csr(const float* __restrict__ adj, float* __restrict__ dinv,
                          int* __restrict__ cnts, int* __restrict__ cols) {
    int r = (blockIdx.x * blockDim.x + threadIdx.x) >> 6;
    int lane = threadIdx.x & 63;
    if (r >= NROWS) return;
    const float* row = adj + (size_t)r * NROWS;
    int* mycols = cols + (size_t)r * CAP;
    int cnt = 0;
    for (int base = 0; base < NROWS; base += 64) {
        float v = row[base + lane];
        bool nz = (v != 0.0f);
        unsigned long long m = __ballot(nz);
        if (nz) {
            int pre = __popcll(m & ((1ull << lane) - 1ull));
            int pos = cnt + pre;
            if (pos < CAP) mycols[pos] = base + lane;
        }
        cnt += __popcll(m);
    }
    if (lane == 0) {
        cnts[r] = cnt < CAP ? cnt : CAP;
        dinv[r] = rsqrtf((float)cnt + 1.0f);
    }
}

// ---------------------------------------------------------------------------
// Kernel 2: h = 0.9*relu(x @ fc_in_w + b) + 0.1*c ; h0 = h
// block = 128 threads (one col each), 8 rows per block.
// ---------------------------------------------------------------------------
__global__ void k_fcin(const float* __restrict__ x, const float* __restrict__ w,
                       const float* __restrict__ b, const float* __restrict__ c,
                       float* __restrict__ h, float* __restrict__ h0) {
    __shared__ float xs[8][NFEATD];
    int col = threadIdx.x;
    int r0 = blockIdx.x * 8;
    for (int rr = 0; rr < 8; ++rr)
        for (int k = col; k < NFEATD; k += 128)
            xs[rr][k] = x[(size_t)(r0 + rr) * NFEATD + k];
    __syncthreads();
    float bias = b[col];
    float acc[8];
#pragma unroll
    for (int rr = 0; rr < 8; ++rr) acc[rr] = bias;
    for (int k = 0; k < NFEATD; ++k) {
        float wv = w[k * NHID + col];
#pragma unroll
        for (int rr = 0; rr < 8; ++rr) acc[rr] += xs[rr][k] * wv;
    }
    float cv = c[col];
#pragma unroll
    for (int rr = 0; rr < 8; ++rr) {
        float hv = 0.9f * fmaxf(acc[rr], 0.0f) + 0.1f * cv;
        h[(size_t)(r0 + rr) * NHID + col] = hv;
        h0[(size_t)(r0 + rr) * NHID + col] = hv;
    }
}

// ---------------------------------------------------------------------------
// Kernel 3: out = hin @ w   (128x128 GEMM, no bias). 16 rows per block of 256.
// ---------------------------------------------------------------------------
__global__ void k_mm128(const float* __restrict__ hin, const float* __restrict__ w,
                        float* __restrict__ out) {
    __shared__ float hs[16][NHID];
    int col = threadIdx.x & 127;
    int rg = threadIdx.x >> 7;   // 0/1
    int r0 = blockIdx.x * 16;
    for (int idx = threadIdx.x; idx < 16 * NHID; idx += 256)
        hs[idx >> 7][idx & 127] = hin[(size_t)r0 * NHID + idx];
    __syncthreads();
    float acc[8] = {0, 0, 0, 0, 0, 0, 0, 0};
    for (int k = 0; k < NHID; ++k) {
        float wv = w[k * NHID + col];
#pragma unroll
        for (int rr = 0; rr < 8; ++rr) acc[rr] += hs[rg * 8 + rr][k] * wv;
    }
#pragma unroll
    for (int rr = 0; rr < 8; ++rr)
        out[(size_t)(r0 + rg * 8 + rr) * NHID + col] = acc[rr];
}

// ---------------------------------------------------------------------------
// Kernel 4: dual SpMM. One wave per row, lane handles cols {lane, lane+64}.
//   lin[i] = dinv[i]*(sum_j dinv[j]*t1[j] + dinv[i]*t1[i]) + b_lin
//   s[i]   = 0.9*dinv[i]*(sum_j dinv[j]*h[j] + dinv[i]*h[i]) + 0.1*h0[i]
// ---------------------------------------------------------------------------
__global__ void k_spmm_dual(const float* __restrict__ t1, const float* __restrict__ h,
                            const float* __restrict__ h0, const float* __restrict__ dinv,
                            const int* __restrict__ cnts, const int* __restrict__ cols,
                            const float* __restrict__ blin, float* __restrict__ lin,
                            float* __restrict__ s) {
    int r = (blockIdx.x * blockDim.x + threadIdx.x) >> 6;
    int lane = threadIdx.x & 63;
    if (r >= NROWS) return;
    int n = cnts[r];
    const int* mycols = cols + (size_t)r * CAP;
    float a0 = 0.f, a1 = 0.f, b0 = 0.f, b1 = 0.f;
    for (int e = 0; e < n; ++e) {
        int j = mycols[e];
        float dj = dinv[j];
        const float* t1r = t1 + (size_t)j * NHID;
        const float* hr  = h  + (size_t)j * NHID;
        a0 += dj * t1r[lane];
        a1 += dj * t1r[64 + lane];
        b0 += dj * hr[lane];
        b1 += dj * hr[64 + lane];
    }
    float di = dinv[r];
    const float* t1i = t1 + (size_t)r * NHID;
    const float* hi  = h  + (size_t)r * NHID;
    a0 += di * t1i[lane];       a1 += di * t1i[64 + lane];
    b0 += di * hi[lane];        b1 += di * hi[64 + lane];
    size_t o = (size_t)r * NHID;
    lin[o + lane]      = di * a0 + blin[lane];
    lin[o + 64 + lane] = di * a1 + blin[64 + lane];
    s[o + lane]      = 0.9f * di * b0 + 0.1f * h0[o + lane];
    s[o + 64 + lane] = 0.9f * di * b1 + 0.1f * h0[o + 64 + lane];
}

// ---------------------------------------------------------------------------
// Kernel 5: h = lin + relu((1-beta)*s + beta*(s @ w) + bg)
// ---------------------------------------------------------------------------
__global__ void k_gcnii(const float* __restrict__ s, const float* __restrict__ lin,
                        const float* __restrict__ w, const float* __restrict__ bg,
                        float beta, float* __restrict__ hout) {
    __shared__ float ss[16][NHID];
    int col = threadIdx.x & 127;
    int rg = threadIdx.x >> 7;
    int r0 = blockIdx.x * 16;
    for (int idx = threadIdx.x; idx < 16 * NHID; idx += 256)
        ss[idx >> 7][idx & 127] = s[(size_t)r0 * NHID + idx];
    __syncthreads();
    float acc[8] = {0, 0, 0, 0, 0, 0, 0, 0};
    for (int k = 0; k < NHID; ++k) {
        float wv = w[k * NHID + col];
#pragma unroll
        for (int rr = 0; rr < 8; ++rr) acc[rr] += ss[rg * 8 + rr][k] * wv;
    }
    float bgv = bg[col];
    float omb = 1.0f - beta;
#pragma unroll
    for (int rr = 0; rr < 8; ++rr) {
        int row = r0 + rg * 8 + rr;
        float sv = ss[rg * 8 + rr][col];
        float g = fmaxf(omb * sv + beta * acc[rr] + bgv, 0.0f);
        hout[(size_t)row * NHID + col] = lin[(size_t)row * NHID + col] + g;
    }
}

// ---------------------------------------------------------------------------
// Kernel 6: out = h @ fc_out_w + fc_out_b   (128x40). 4 rows x 64 threads.
// ---------------------------------------------------------------------------
__global__ void k_fcout(const float* __restrict__ h, const float* __restrict__ w,
                        const float* __restrict__ b, float* __restrict__ out) {
    __shared__ float hs[4][NHID];
    int tid = threadIdx.x;
    int rr = tid >> 6, col = tid & 63;
    int r0 = blockIdx.x * 4;
    for (int idx = tid; idx < 4 * NHID; idx += 256)
        hs[idx >> 7][idx & 127] = h[(size_t)r0 * NHID + idx];
    __syncthreads();
    if (col < NCLS) {
        float acc = b[col];
        for (int k = 0; k < NHID; ++k) acc += hs[rr][k] * w[k * NCLS + col];
        out[(size_t)(r0 + rr) * NCLS + col] = acc;
    }
}

extern "C" void kernel_launch(void* const* d_in, const int* in_sizes, int n_in,
                              void* d_out, int out_size, void* d_ws, size_t ws_size,
                              hipStream_t stream) {
    const float* x        = (const float*)d_in[0];
    const float* adj      = (const float*)d_in[1];
    const float* fc_in_w  = (const float*)d_in[2];
    const float* fc_in_b  = (const float*)d_in[3];
    const float* c        = (const float*)d_in[4];
    const float* w_gcnii  = (const float*)d_in[5];
    const float* b_gcnii  = (const float*)d_in[6];
    const float* w_lin    = (const float*)d_in[7];
    const float* b_lin    = (const float*)d_in[8];
    const float* fc_out_w = (const float*)d_in[9];
    const float* fc_out_b = (const float*)d_in[10];
    float* out = (float*)d_out;

    char* ws = (char*)d_ws;
    size_t off = 0;
    auto alloc = [&](size_t bytes) -> void* {
        void* p = ws + off;
        off += (bytes + 255) & ~(size_t)255;
        return p;
    };
    float* dinv = (float*)alloc((size_t)NROWS * 4);
    int*   cnts = (int*)  alloc((size_t)NROWS * 4);
    int*   cols = (int*)  alloc((size_t)NROWS * CAP * 4);
    float* h    = (float*)alloc((size_t)NROWS * NHID * 4);
    float* h0   = (float*)alloc((size_t)NROWS * NHID * 4);
    float* t1   = (float*)alloc((size_t)NROWS * NHID * 4);
    float* lin  = (float*)alloc((size_t)NROWS * NHID * 4);
    float* sbuf = (float*)alloc((size_t)NROWS * NHID * 4);

    k_deg_csr<<<NROWS / 4, 256, 0, stream>>>(adj, dinv, cnts, cols);
    k_fcin<<<NROWS / 8, 128, 0, stream>>>(x, fc_in_w, fc_in_b, c, h, h0);

    for (int i = 0; i < 4; ++i) {
        float beta = logf(0.5f / (float)(i + 1) + 1.0f);
        k_mm128<<<NROWS / 16, 256, 0, stream>>>(h, w_lin + (size_t)i * NHID * NHID, t1);
        k_spmm_dual<<<NROWS / 4, 256, 0, stream>>>(t1, h, h0, dinv, cnts, cols,
                                                   b_lin + (size_t)i * NHID, lin, sbuf);
        k_gcnii<<<NROWS / 16, 256, 0, stream>>>(sbuf, lin,
                                                w_gcnii + (size_t)i * NHID * NHID,
                                                b_gcnii + (size_t)i * NHID, beta, h);
    }
    k_fcout<<<NROWS / 4, 256, 0, stream>>>(h, fc_out_w, fc_out_b, out);
}

// Round 3
// 294.608 us; speedup vs baseline: 1.1426x; 1.1426x over previous
//
#include <hip/hip_runtime.h>
#include <math.h>

#define NROWS 8192
#define NFEATD 500
#define NHID 128
#define NCLS 40
#define CAP 64   // max nnz/row (actual ~16±4, max ~41 for p=0.002)

typedef float f32x4 __attribute__((ext_vector_type(4)));

// ---------------------------------------------------------------------------
// Kernel 1: degree + CSR build. One wave per row, float4 loads (1KB/wave-inst).
// adj entries are exactly 0.0 or 1.0. deg = rowsum + 1 (identity).
// Column order within a 256-col chunk is component-major; order is irrelevant
// for the SpMM sum (deterministic every call).
// ---------------------------------------------------------------------------
__global__ void k_deg_csr(const float* __restrict__ adj, float* __restrict__ dinv,
                          int* __restrict__ cnts, int* __restrict__ cols) {
    int r = (blockIdx.x * blockDim.x + threadIdx.x) >> 6;
    int lane = threadIdx.x & 63;
    if (r >= NROWS) return;
    const f32x4* row4 = (const f32x4*)(adj + (size_t)r * NROWS);
    int* mycols = cols + (size_t)r * CAP;
    unsigned long long lt = (1ull << lane) - 1ull;
    int cnt = 0;
    for (int it = 0; it < NROWS / 256; ++it) {
        f32x4 v = __builtin_nontemporal_load(&row4[it * 64 + lane]);
        int base = it * 256 + 4 * lane;
        bool nz; unsigned long long m;
        nz = (v.x != 0.0f); m = __ballot(nz);
        if (nz) { int p = cnt + __popcll(m & lt); mycols[p < CAP ? p : CAP - 1] = base; }
        cnt += __popcll(m);
        nz = (v.y != 0.0f); m = __ballot(nz);
        if (nz) { int p = cnt + __popcll(m & lt); mycols[p < CAP ? p : CAP - 1] = base + 1; }
        cnt += __popcll(m);
        nz = (v.z != 0.0f); m = __ballot(nz);
        if (nz) { int p = cnt + __popcll(m & lt); mycols[p < CAP ? p : CAP - 1] = base + 2; }
        cnt += __popcll(m);
        nz = (v.w != 0.0f); m = __ballot(nz);
        if (nz) { int p = cnt + __popcll(m & lt); mycols[p < CAP ? p : CAP - 1] = base + 3; }
        cnt += __popcll(m);
    }
    if (lane == 0) {
        cnts[r] = cnt < CAP ? cnt : CAP;
        dinv[r] = rsqrtf((float)cnt + 1.0f);
    }
}

// ---------------------------------------------------------------------------
// Kernel 2: h = 0.9*relu(x @ fc_in_w + b) + 0.1*c ; h0 = h
// ---------------------------------------------------------------------------
__global__ void k_fcin(const float* __restrict__ x, const float* __restrict__ w,
                       const float* __restrict__ b, const float* __restrict__ c,
                       float* __restrict__ h, float* __restrict__ h0) {
    __shared__ float xs[8][NFEATD];
    int col = threadIdx.x;
    int r0 = blockIdx.x * 8;
    for (int rr = 0; rr < 8; ++rr)
        for (int k = col; k < NFEATD; k += 128)
            xs[rr][k] = x[(size_t)(r0 + rr) * NFEATD + k];
    __syncthreads();
    float bias = b[col];
    float acc[8];
#pragma unroll
    for (int rr = 0; rr < 8; ++rr) acc[rr] = bias;
    for (int k = 0; k < NFEATD; ++k) {
        float wv = w[k * NHID + col];
#pragma unroll
        for (int rr = 0; rr < 8; ++rr) acc[rr] += xs[rr][k] * wv;
    }
    float cv = c[col];
#pragma unroll
    for (int rr = 0; rr < 8; ++rr) {
        float hv = 0.9f * fmaxf(acc[rr], 0.0f) + 0.1f * cv;
        h[(size_t)(r0 + rr) * NHID + col] = hv;
        h0[(size_t)(r0 + rr) * NHID + col] = hv;
    }
}

// ---------------------------------------------------------------------------
// Kernel 3: ah = A_hat @ h. One wave per row, float2 per lane (512B/row gather).
//   ah[i] = dinv[i]*(sum_j dinv[j]*h[j] + dinv[i]*h[i])
// ---------------------------------------------------------------------------
__global__ void k_spmm(const float* __restrict__ h, const float* __restrict__ dinv,
                       const int* __restrict__ cnts, const int* __restrict__ cols,
                       float* __restrict__ ah) {
    int r = (blockIdx.x * blockDim.x + threadIdx.x) >> 6;
    int lane = threadIdx.x & 63;
    if (r >= NROWS) return;
    int n = cnts[r];
    const int* mycols = cols + (size_t)r * CAP;
    float ax = 0.f, ay = 0.f;
    for (int e = 0; e < n; ++e) {
        int j = mycols[e];
        float dj = dinv[j];
        float2 v = ((const float2*)(h + (size_t)j * NHID))[lane];
        ax += dj * v.x;
        ay += dj * v.y;
    }
    float di = dinv[r];
    float2 vi = ((const float2*)(h + (size_t)r * NHID))[lane];
    ax = di * (ax + di * vi.x);
    ay = di * (ay + di * vi.y);
    ((float2*)(ah + (size_t)r * NHID))[lane] = make_float2(ax, ay);
}

// ---------------------------------------------------------------------------
// Kernel 4: fused per-layer epilogue. s = 0.9*ah + 0.1*h0 (in LDS), then
//   h_out = (ah @ w_lin + b_lin) + relu((1-beta)*s + beta*(s @ w_g) + b_g)
// block = 256 threads, 16 rows/block, two GEMM accumulators per thread.
// ---------------------------------------------------------------------------
__global__ void k_fused(const float* __restrict__ ah, const float* __restrict__ h0,
                        const float* __restrict__ wlin, const float* __restrict__ blin,
                        const float* __restrict__ wg, const float* __restrict__ bg,
                        float beta, float* __restrict__ hout) {
    __shared__ float ahs[16][NHID];
    __shared__ float ss[16][NHID];
    int col = threadIdx.x & 127;
    int rg = threadIdx.x >> 7;   // 0/1
    int r0 = blockIdx.x * 16;
    for (int idx = threadIdx.x; idx < 16 * NHID; idx += 256) {
        float av = ah[(size_t)r0 * NHID + idx];
        float hv = h0[(size_t)r0 * NHID + idx];
        ahs[idx >> 7][idx & 127] = av;
        ss[idx >> 7][idx & 127] = 0.9f * av + 0.1f * hv;
    }
    __syncthreads();
    float accl[8] = {0, 0, 0, 0, 0, 0, 0, 0};
    float accg[8] = {0, 0, 0, 0, 0, 0, 0, 0};
    for (int k = 0; k < NHID; ++k) {
        float wl = wlin[k * NHID + col];
        float wv = wg[k * NHID + col];
#pragma unroll
        for (int rr = 0; rr < 8; ++rr) {
            accl[rr] += ahs[rg * 8 + rr][k] * wl;
            accg[rr] += ss[rg * 8 + rr][k] * wv;
        }
    }
    float blv = blin[col];
    float bgv = bg[col];
    float omb = 1.0f - beta;
#pragma unroll
    for (int rr = 0; rr < 8; ++rr) {
        int row = r0 + rg * 8 + rr;
        float sv = ss[rg * 8 + rr][col];
        float g = fmaxf(omb * sv + beta * accg[rr] + bgv, 0.0f);
        hout[(size_t)row * NHID + col] = (accl[rr] + blv) + g;
    }
}

// ---------------------------------------------------------------------------
// Kernel 5: out = h @ fc_out_w + fc_out_b   (128x40). 4 rows x 64 threads.
// ---------------------------------------------------------------------------
__global__ void k_fcout(const float* __restrict__ h, const float* __restrict__ w,
                        const float* __restrict__ b, float* __restrict__ out) {
    __shared__ float hs[4][NHID];
    int tid = threadIdx.x;
    int rr = tid >> 6, col = tid & 63;
    int r0 = blockIdx.x * 4;
    for (int idx = tid; idx < 4 * NHID; idx += 256)
        hs[idx >> 7][idx & 127] = h[(size_t)r0 * NHID + idx];
    __syncthreads();
    if (col < NCLS) {
        float acc = b[col];
        for (int k = 0; k < NHID; ++k) acc += hs[rr][k] * w[k * NCLS + col];
        out[(size_t)(r0 + rr) * NCLS + col] = acc;
    }
}

extern "C" void kernel_launch(void* const* d_in, const int* in_sizes, int n_in,
                              void* d_out, int out_size, void* d_ws, size_t ws_size,
                              hipStream_t stream) {
    const float* x        = (const float*)d_in[0];
    const float* adj      = (const float*)d_in[1];
    const float* fc_in_w  = (const float*)d_in[2];
    const float* fc_in_b  = (const float*)d_in[3];
    const float* c        = (const float*)d_in[4];
    const float* w_gcnii  = (const float*)d_in[5];
    const float* b_gcnii  = (const float*)d_in[6];
    const float* w_lin    = (const float*)d_in[7];
    const float* b_lin    = (const float*)d_in[8];
    const float* fc_out_w = (const float*)d_in[9];
    const float* fc_out_b = (const float*)d_in[10];
    float* out = (float*)d_out;

    char* ws = (char*)d_ws;
    size_t off = 0;
    auto alloc = [&](size_t bytes) -> void* {
        void* p = ws + off;
        off += (bytes + 255) & ~(size_t)255;
        return p;
    };
    float* dinv = (float*)alloc((size_t)NROWS * 4);
    int*   cnts = (int*)  alloc((size_t)NROWS * 4);
    int*   cols = (int*)  alloc((size_t)NROWS * CAP * 4);
    float* h    = (float*)alloc((size_t)NROWS * NHID * 4);
    float* h0   = (float*)alloc((size_t)NROWS * NHID * 4);
    float* ah   = (float*)alloc((size_t)NROWS * NHID * 4);

    // fcin first (clean caches), then the adj stream (nontemporal anyway).
    k_fcin<<<NROWS / 8, 128, 0, stream>>>(x, fc_in_w, fc_in_b, c, h, h0);
    k_deg_csr<<<NROWS / 4, 256, 0, stream>>>(adj, dinv, cnts, cols);

    for (int i = 0; i < 4; ++i) {
        float beta = logf(0.5f / (float)(i + 1) + 1.0f);
        k_spmm<<<NROWS / 4, 256, 0, stream>>>(h, dinv, cnts, cols, ah);
        k_fused<<<NROWS / 16, 256, 0, stream>>>(ah, h0,
                                                w_lin + (size_t)i * NHID * NHID,
                                                b_lin + (size_t)i * NHID,
                                                w_gcnii + (size_t)i * NHID * NHID,
                                                b_gcnii + (size_t)i * NHID,
                                                beta, h);
    }
    k_fcout<<<NROWS / 4, 256, 0, stream>>>(h, fc_out_w, fc_out_b, out);
}

// Round 4
// 211.127 us; speedup vs baseline: 1.5944x; 1.3954x over previous
//
#include <hip/hip_runtime.h>
#include <math.h>

#define NROWS 8192
#define NFEATD 500
#define NHID 128
#define NCLS 40
#define CAP 64            // max nnz/row (mean ~16.4, binomial max ~41)
#define FCIN_BLOCKS (NROWS / 8)   // 1024
#define CSR_BLOCKS  (NROWS / 4)   // 2048

typedef float f32x4 __attribute__((ext_vector_type(4)));

// ---------------------------------------------------------------------------
// Kernel 1 (heterogeneous): blocks [0,1024) do fcin, blocks [1024,3072) do
// CSR build. The BW-bound adj stream overlaps the VALU-bound fcin GEMM.
//   fcin: h = 0.9*relu(x @ fc_in_w + b) + 0.1*c ; h0 = h
//   csr : ordered nonzero columns per row + dinv = rsqrt(deg+1)
// ---------------------------------------------------------------------------
__global__ __launch_bounds__(256) void k_pre(
    const float* __restrict__ x, const float* __restrict__ w,
    const float* __restrict__ b, const float* __restrict__ c,
    const float* __restrict__ adj,
    float* __restrict__ h, float* __restrict__ h0,
    float* __restrict__ dinv, int* __restrict__ cnts, int* __restrict__ cols)
{
    __shared__ float xs[8][504];          // 504 stride: 16B-aligned rows
    int tid = threadIdx.x;
    if (blockIdx.x < FCIN_BLOCKS) {
        int col = tid & 127;
        int rg = tid >> 7;                // rows rg*4 .. rg*4+3
        int r0 = blockIdx.x * 8;
        for (int rr = 0; rr < 8; ++rr)
            for (int k = tid; k < NFEATD; k += 256)
                xs[rr][k] = x[(size_t)(r0 + rr) * NFEATD + k];
        __syncthreads();
        float bias = b[col];
        float acc[4] = {bias, bias, bias, bias};
        for (int k4 = 0; k4 < NFEATD / 4; ++k4) {
            int k = k4 * 4;
            f32x4 a0 = *(const f32x4*)&xs[rg * 4 + 0][k];
            f32x4 a1 = *(const f32x4*)&xs[rg * 4 + 1][k];
            f32x4 a2 = *(const f32x4*)&xs[rg * 4 + 2][k];
            f32x4 a3 = *(const f32x4*)&xs[rg * 4 + 3][k];
            float w0 = w[(k + 0) * NHID + col];
            float w1 = w[(k + 1) * NHID + col];
            float w2 = w[(k + 2) * NHID + col];
            float w3 = w[(k + 3) * NHID + col];
            acc[0] += a0.x * w0 + a0.y * w1 + a0.z * w2 + a0.w * w3;
            acc[1] += a1.x * w0 + a1.y * w1 + a1.z * w2 + a1.w * w3;
            acc[2] += a2.x * w0 + a2.y * w1 + a2.z * w2 + a2.w * w3;
            acc[3] += a3.x * w0 + a3.y * w1 + a3.z * w2 + a3.w * w3;
        }
        float cv = c[col];
#pragma unroll
        for (int rr = 0; rr < 4; ++rr) {
            float hv = 0.9f * fmaxf(acc[rr], 0.0f) + 0.1f * cv;
            size_t o = (size_t)(r0 + rg * 4 + rr) * NHID + col;
            h[o] = hv;
            h0[o] = hv;
        }
    } else {
        int bid = blockIdx.x - FCIN_BLOCKS;
        int r = bid * 4 + (tid >> 6);
        int lane = tid & 63;
        const f32x4* row4 = (const f32x4*)(adj + (size_t)r * NROWS);
        int* mycols = cols + (size_t)r * CAP;
        unsigned long long lt = (1ull << lane) - 1ull;
        int cnt = 0;
        for (int it = 0; it < NROWS / 256; ++it) {
            f32x4 v = __builtin_nontemporal_load(&row4[it * 64 + lane]);
            int base = it * 256 + 4 * lane;
            bool nz; unsigned long long m;
            nz = (v.x != 0.0f); m = __ballot(nz);
            if (nz) { int p = cnt + __popcll(m & lt); mycols[p < CAP ? p : CAP - 1] = base; }
            cnt += __popcll(m);
            nz = (v.y != 0.0f); m = __ballot(nz);
            if (nz) { int p = cnt + __popcll(m & lt); mycols[p < CAP ? p : CAP - 1] = base + 1; }
            cnt += __popcll(m);
            nz = (v.z != 0.0f); m = __ballot(nz);
            if (nz) { int p = cnt + __popcll(m & lt); mycols[p < CAP ? p : CAP - 1] = base + 2; }
            cnt += __popcll(m);
            nz = (v.w != 0.0f); m = __ballot(nz);
            if (nz) { int p = cnt + __popcll(m & lt); mycols[p < CAP ? p : CAP - 1] = base + 3; }
            cnt += __popcll(m);
        }
        if (lane == 0) {
            cnts[r] = cnt < CAP ? cnt : CAP;
            dinv[r] = rsqrtf((float)cnt + 1.0f);
        }
    }
}

// ---------------------------------------------------------------------------
// Kernel 2 (per layer, fused): gather ah = A_hat@h into LDS (ahs), form
// s = 0.9*ah + 0.1*h0 (ss), then
//   h_out = (ahs @ w_lin + b_lin) + relu((1-beta)*ss + beta*(ss @ w_g) + b_g)
// 8 rows/block, 256 threads (4 waves: gather 2 rows each; GEMM 4 rows x col).
// ---------------------------------------------------------------------------
__global__ __launch_bounds__(256) void k_layer(
    const float* __restrict__ hin, const float* __restrict__ h0,
    const float* __restrict__ dinv, const int* __restrict__ cnts,
    const int* __restrict__ cols,
    const float* __restrict__ wlin, const float* __restrict__ blin,
    const float* __restrict__ wg, const float* __restrict__ bg,
    float beta, float* __restrict__ hout)
{
    __shared__ float ahs[8][NHID];
    __shared__ float ss[8][NHID];
    int tid = threadIdx.x;
    int lane = tid & 63;
    int wid = tid >> 6;                   // 0..3
    int r0 = blockIdx.x * 8;

    // ---- gather phase: wave wid handles rows 2*wid, 2*wid+1 ----
    for (int rr = 2 * wid; rr < 2 * wid + 2; ++rr) {
        int r = r0 + rr;
        int n = cnts[r];
        const int* mc = cols + (size_t)r * CAP;
        float ax = 0.f, ay = 0.f;
        int e = 0;
        for (; e + 4 <= n; e += 4) {
            int j0 = mc[e], j1 = mc[e + 1], j2 = mc[e + 2], j3 = mc[e + 3];
            float d0 = dinv[j0], d1 = dinv[j1], d2 = dinv[j2], d3 = dinv[j3];
            float2 v0 = ((const float2*)(hin + (size_t)j0 * NHID))[lane];
            float2 v1 = ((const float2*)(hin + (size_t)j1 * NHID))[lane];
            float2 v2 = ((const float2*)(hin + (size_t)j2 * NHID))[lane];
            float2 v3 = ((const float2*)(hin + (size_t)j3 * NHID))[lane];
            ax += d0 * v0.x + d1 * v1.x + d2 * v2.x + d3 * v3.x;
            ay += d0 * v0.y + d1 * v1.y + d2 * v2.y + d3 * v3.y;
        }
        for (; e < n; ++e) {
            int j = mc[e];
            float dj = dinv[j];
            float2 v = ((const float2*)(hin + (size_t)j * NHID))[lane];
            ax += dj * v.x;
            ay += dj * v.y;
        }
        float di = dinv[r];
        float2 vi = ((const float2*)(hin + (size_t)r * NHID))[lane];
        ax = di * (ax + di * vi.x);
        ay = di * (ay + di * vi.y);
        float2 h0v = ((const float2*)(h0 + (size_t)r * NHID))[lane];
        ((float2*)&ahs[rr][0])[lane] = make_float2(ax, ay);
        ((float2*)&ss[rr][0])[lane] =
            make_float2(0.9f * ax + 0.1f * h0v.x, 0.9f * ay + 0.1f * h0v.y);
    }
    __syncthreads();

    // ---- GEMM phase: thread = (rg rows group, col) ----
    int col = tid & 127;
    int rg = tid >> 7;
    float accl[4] = {0, 0, 0, 0};
    float accg[4] = {0, 0, 0, 0};
    for (int k4 = 0; k4 < NHID / 4; ++k4) {
        int k = k4 * 4;
        f32x4 a0 = *(const f32x4*)&ahs[rg * 4 + 0][k];
        f32x4 a1 = *(const f32x4*)&ahs[rg * 4 + 1][k];
        f32x4 a2 = *(const f32x4*)&ahs[rg * 4 + 2][k];
        f32x4 a3 = *(const f32x4*)&ahs[rg * 4 + 3][k];
        f32x4 s0 = *(const f32x4*)&ss[rg * 4 + 0][k];
        f32x4 s1 = *(const f32x4*)&ss[rg * 4 + 1][k];
        f32x4 s2 = *(const f32x4*)&ss[rg * 4 + 2][k];
        f32x4 s3 = *(const f32x4*)&ss[rg * 4 + 3][k];
        float wl0 = wlin[(k + 0) * NHID + col];
        float wl1 = wlin[(k + 1) * NHID + col];
        float wl2 = wlin[(k + 2) * NHID + col];
        float wl3 = wlin[(k + 3) * NHID + col];
        float wg0 = wg[(k + 0) * NHID + col];
        float wg1 = wg[(k + 1) * NHID + col];
        float wg2 = wg[(k + 2) * NHID + col];
        float wg3 = wg[(k + 3) * NHID + col];
        accl[0] += a0.x * wl0 + a0.y * wl1 + a0.z * wl2 + a0.w * wl3;
        accl[1] += a1.x * wl0 + a1.y * wl1 + a1.z * wl2 + a1.w * wl3;
        accl[2] += a2.x * wl0 + a2.y * wl1 + a2.z * wl2 + a2.w * wl3;
        accl[3] += a3.x * wl0 + a3.y * wl1 + a3.z * wl2 + a3.w * wl3;
        accg[0] += s0.x * wg0 + s0.y * wg1 + s0.z * wg2 + s0.w * wg3;
        accg[1] += s1.x * wg0 + s1.y * wg1 + s1.z * wg2 + s1.w * wg3;
        accg[2] += s2.x * wg0 + s2.y * wg1 + s2.z * wg2 + s2.w * wg3;
        accg[3] += s3.x * wg0 + s3.y * wg1 + s3.z * wg2 + s3.w * wg3;
    }
    float blv = blin[col], bgv = bg[col], omb = 1.0f - beta;
#pragma unroll
    for (int rr = 0; rr < 4; ++rr) {
        int row = r0 + rg * 4 + rr;
        float sv = ss[rg * 4 + rr][col];
        float g = fmaxf(omb * sv + beta * accg[rr] + bgv, 0.0f);
        hout[(size_t)row * NHID + col] = accl[rr] + blv + g;
    }
}

// ---------------------------------------------------------------------------
// Kernel 3: out = h @ fc_out_w + fc_out_b   (128x40). 4 rows x 64 threads.
// ---------------------------------------------------------------------------
__global__ void k_fcout(const float* __restrict__ h, const float* __restrict__ w,
                        const float* __restrict__ b, float* __restrict__ out) {
    __shared__ float hs[4][NHID];
    int tid = threadIdx.x;
    int rr = tid >> 6, col = tid & 63;
    int r0 = blockIdx.x * 4;
    for (int idx = tid; idx < 4 * NHID; idx += 256)
        hs[idx >> 7][idx & 127] = h[(size_t)r0 * NHID + idx];
    __syncthreads();
    if (col < NCLS) {
        float acc = b[col];
        for (int k = 0; k < NHID; ++k) acc += hs[rr][k] * w[k * NCLS + col];
        out[(size_t)(r0 + rr) * NCLS + col] = acc;
    }
}

extern "C" void kernel_launch(void* const* d_in, const int* in_sizes, int n_in,
                              void* d_out, int out_size, void* d_ws, size_t ws_size,
                              hipStream_t stream) {
    const float* x        = (const float*)d_in[0];
    const float* adj      = (const float*)d_in[1];
    const float* fc_in_w  = (const float*)d_in[2];
    const float* fc_in_b  = (const float*)d_in[3];
    const float* c        = (const float*)d_in[4];
    const float* w_gcnii  = (const float*)d_in[5];
    const float* b_gcnii  = (const float*)d_in[6];
    const float* w_lin    = (const float*)d_in[7];
    const float* b_lin    = (const float*)d_in[8];
    const float* fc_out_w = (const float*)d_in[9];
    const float* fc_out_b = (const float*)d_in[10];
    float* out = (float*)d_out;

    char* ws = (char*)d_ws;
    size_t off = 0;
    auto alloc = [&](size_t bytes) -> void* {
        void* p = ws + off;
        off += (bytes + 255) & ~(size_t)255;
        return p;
    };
    float* dinv = (float*)alloc((size_t)NROWS * 4);
    int*   cnts = (int*)  alloc((size_t)NROWS * 4);
    int*   cols = (int*)  alloc((size_t)NROWS * CAP * 4);
    float* hA   = (float*)alloc((size_t)NROWS * NHID * 4);
    float* hB   = (float*)alloc((size_t)NROWS * NHID * 4);
    float* h0   = (float*)alloc((size_t)NROWS * NHID * 4);

    k_pre<<<FCIN_BLOCKS + CSR_BLOCKS, 256, 0, stream>>>(
        x, fc_in_w, fc_in_b, c, adj, hA, h0, dinv, cnts, cols);

    float* bufs[2] = {hA, hB};
    for (int i = 0; i < 4; ++i) {
        float beta = logf(0.5f / (float)(i + 1) + 1.0f);
        k_layer<<<NROWS / 8, 256, 0, stream>>>(
            bufs[i & 1], h0, dinv, cnts, cols,
            w_lin + (size_t)i * NHID * NHID, b_lin + (size_t)i * NHID,
            w_gcnii + (size_t)i * NHID * NHID, b_gcnii + (size_t)i * NHID,
            beta, bufs[(i + 1) & 1]);
    }
    k_fcout<<<NROWS / 4, 256, 0, stream>>>(bufs[0], fc_out_w, fc_out_b, out);
}